// Round 11
// baseline (464.500 us; speedup 1.0000x reference)
//
#include <hip/hip_runtime.h>
#include <stdint.h>

// ---------------------------------------------------------------------------
// ThirdOrderAttention: B=1, N=256, C=512, H=8, D=64
// Flash attention over virtual L=65536 KV (K'=kj*kk, V'=vj*vk), bf16 MFMA.
// R11: R9 skeleton (256 thr, (256,2), flat 32-slice stream, AGPR acc, single
// tree-reduce epilogue) + dual per-j accumulators so the PV A-operand is raw
// pre-cast bf16 vk^T (zero F-build VALU); vj applied once in the epilogue
// (yv = acc0*vs0 + acc1*vs1). AGPR 128 + arch ~110 fits (256,2) budget.
// Spill tripwire: FETCH >= 100 MB -> revert to R9.
// ---------------------------------------------------------------------------

typedef __attribute__((ext_vector_type(4))) float f32x4;
typedef __attribute__((ext_vector_type(4))) short s16x4;
typedef __attribute__((ext_vector_type(8))) short s16x8;

#define H_ 8
#define N_ 256
#define D_ 64
#define C_ 512
#define NC5 2560
#define SCALE_LOG2E 0.1803368801111204f  // 0.125 * log2(e): P = exp2(S')

// ----- bf16 helpers --------------------------------------------------------
__device__ __forceinline__ unsigned short f2bf_rne(float x) {
  union { float f; unsigned u; } a; a.f = x;
  unsigned r = a.u + 0x7fffu + ((a.u >> 16) & 1u);
  return (unsigned short)(r >> 16);
}

__device__ __forceinline__ unsigned pk_bf16(float a, float b) {
#if __has_builtin(__builtin_amdgcn_cvt_pk_bf16_f32)
  typedef __attribute__((ext_vector_type(2))) __bf16 bf16x2;
  union { bf16x2 v; unsigned u; } u;
  u.v = __builtin_amdgcn_cvt_pk_bf16_f32(a, b);
  return u.u;
#else
  return (unsigned)f2bf_rne(a) | ((unsigned)f2bf_rne(b) << 16);
#endif
}

// ----- MFMA wrappers -------------------------------------------------------
__device__ __forceinline__ f32x4 mfma32(s16x8 a, s16x8 b, f32x4 c) {
  return __builtin_amdgcn_mfma_f32_16x16x32_bf16(a, b, c, 0, 0, 0);
}

__device__ __forceinline__ f32x4 mfma16(s16x4 a, s16x4 b, f32x4 c) {
#if __has_builtin(__builtin_amdgcn_mfma_f32_16x16x16bf16_1k)
  return __builtin_amdgcn_mfma_f32_16x16x16bf16_1k(a, b, c, 0, 0, 0);
#else
  asm volatile("s_nop 1\n\t"
               "v_mfma_f32_16x16x16_bf16 %0, %1, %2, %0\n\t"
               "s_nop 7\n\t"
               "s_nop 2"
               : "+v"(c) : "v"(a), "v"(b));
  return c;
#endif
}

// ---------------------------------------------------------------------------
// Kernel 1: projection GEMM  p = x[256,512] @ W_att[512,2560] + b_att
// BM=16, BN=64, BK=32; 256 threads; 1x4 micro-tile. Grid (40, 16) = 640 blks.
// Epilogue: qS f32 (pre-scaled), kj f32, kk bf16 [H][N][D], vj f32,
//           vk^T bf16 [H][D][N].
// ---------------------------------------------------------------------------
__global__ __launch_bounds__(256) void proj_kernel(
    const float* __restrict__ x, const float* __restrict__ W,
    const float* __restrict__ b,
    float* __restrict__ qS, float* __restrict__ kj,
    unsigned short* __restrict__ kkB, float* __restrict__ vj,
    unsigned short* __restrict__ vkBT) {
  __shared__ float As[32][17];
  __shared__ float Bs[32][68];
  const int bx = blockIdx.x;  // 40 col tiles of 64
  const int by = blockIdx.y;  // 16 row tiles of 16
  const int tid = threadIdx.x;
  const int m = tid >> 4;        // 0..15 output row
  const int c4 = (tid & 15) * 4; // output col group
  float acc0 = 0.f, acc1 = 0.f, acc2 = 0.f, acc3 = 0.f;

  const int lk = tid & 31;   // A-load k
  const int lm = tid >> 5;   // A-load m (0..7), +8 second half
  const int bk = tid >> 4;   // B-load k (0..15), +16 second half

  for (int k0 = 0; k0 < C_; k0 += 32) {
    As[lk][lm] = x[(by * 16 + lm) * C_ + k0 + lk];
    As[lk][lm + 8] = x[(by * 16 + lm + 8) * C_ + k0 + lk];
    *(f32x4*)&Bs[bk][c4] = *(const f32x4*)&W[(k0 + bk) * NC5 + bx * 64 + c4];
    *(f32x4*)&Bs[bk + 16][c4] =
        *(const f32x4*)&W[(k0 + bk + 16) * NC5 + bx * 64 + c4];
    __syncthreads();
#pragma unroll
    for (int kq = 0; kq < 32; ++kq) {
      float a = As[kq][m];
      f32x4 bv = *(const f32x4*)&Bs[kq][c4];
      acc0 += a * bv.x; acc1 += a * bv.y; acc2 += a * bv.z; acc3 += a * bv.w;
    }
    __syncthreads();
  }

  const int i = by * 16 + m;
  const int col0 = bx * 64 + c4;
  const int h = (bx * 64) / 320;
  const int part = ((bx * 64) % 320) >> 6;
  const int d0 = c4;
  float v0 = acc0 + b[col0 + 0];
  float v1 = acc1 + b[col0 + 1];
  float v2 = acc2 + b[col0 + 2];
  float v3 = acc3 + b[col0 + 3];
  const int idx = (h * N_ + i) * D_ + d0;
  if (part == 0) {
    f32x4 o = {v0 * SCALE_LOG2E, v1 * SCALE_LOG2E, v2 * SCALE_LOG2E,
               v3 * SCALE_LOG2E};
    *(f32x4*)(qS + idx) = o;
  } else if (part == 1) {
    f32x4 o = {v0, v1, v2, v3};
    *(f32x4*)(kj + idx) = o;
  } else if (part == 2) {
    union { unsigned u[2]; s16x4 v4; } t;
    t.u[0] = pk_bf16(v0, v1);
    t.u[1] = pk_bf16(v2, v3);
    *(s16x4*)(kkB + idx) = t.v4;
  } else if (part == 3) {
    f32x4 o = {v0, v1, v2, v3};
    *(f32x4*)(vj + idx) = o;
  } else {
    vkBT[(h * D_ + d0 + 0) * N_ + i] = f2bf_rne(v0);
    vkBT[(h * D_ + d0 + 1) * N_ + i] = f2bf_rne(v1);
    vkBT[(h * D_ + d0 + 2) * N_ + i] = f2bf_rne(v2);
    vkBT[(h * D_ + d0 + 3) * N_ + i] = f2bf_rne(v3);
  }
}

// ---------------------------------------------------------------------------
// Kernel 2: fused third-order flash attention (R9 skeleton, dual per-j acc).
// Grid (32 jc, 4 ic, 8 h) = 1024 blocks x 256 thr (4 waves); wave owns 2 j.
// Per (k0, 16-t slice): S^T = kk_bf16 . q~ (q~ = bf16(qS*kj)); P = exp2(S');
// S^T C-layout == mfma16 B-layout -> G_j^T[d,i] += vkB^T[d,t16] @ P^T with
// raw bf16 A-operand (no F-build VALU). acc0/acc1 AGPR-resident; vj applied
// once in the epilogue: yv = acc0*vj0 + acc1*vj1; then R9's tree reduce.
// ---------------------------------------------------------------------------
__global__ __launch_bounds__(256, 2) void flash3_kernel(
    const float* __restrict__ qS,            // [H][N][D] f32, pre-scaled
    const float* __restrict__ kjF,           // [H][N][D] f32
    const unsigned short* __restrict__ kkB,  // [H][N][D] bf16
    const float* __restrict__ vjF,           // [H][N][D] f32
    const unsigned short* __restrict__ vkBT, // [H][D][N] bf16
    float* __restrict__ slab,                // [H][32][4][64][64]
    float* __restrict__ lslab) {             // [H][32][256]
  const int jc = blockIdx.x;
  const int ic = blockIdx.y;
  const int h = blockIdx.z;
  const int wave = threadIdx.x >> 6;
  const int lane = threadIdx.x & 63;
  const int q = lane >> 4;
  const int c = lane & 15;
  const int i0 = ic * 64;

  const float* qh = qS + h * (N_ * D_);
  const float* kjh = kjF + h * (N_ * D_);
  const unsigned short* kkh = kkB + h * (N_ * D_);
  const float* vjh = vjF + h * (N_ * D_);
  const unsigned short* vkh = vkBT + h * (D_ * N_);

  f32x4 accA[4][4];  // G^T for j0: [md over d][nb over i]
  f32x4 accB[4][4];  // G^T for j1
#pragma unroll
  for (int md = 0; md < 4; ++md)
#pragma unroll
    for (int nb = 0; nb < 4; ++nb) {
      accA[md][nb] = (f32x4){0.f, 0.f, 0.f, 0.f};
      accB[md][nb] = (f32x4){0.f, 0.f, 0.f, 0.f};
    }
  float lac[4] = {0.f, 0.f, 0.f, 0.f};

  for (int jj = 0; jj < 2; ++jj) {
    const int j = jc * 8 + wave * 2 + jj;
    const f32x4 kj0a = *(const f32x4*)(kjh + j * D_ + q * 8);
    const f32x4 kj0b = *(const f32x4*)(kjh + j * D_ + q * 8 + 4);
    const f32x4 kj1a = *(const f32x4*)(kjh + j * D_ + 32 + q * 8);
    const f32x4 kj1b = *(const f32x4*)(kjh + j * D_ + 32 + q * 8 + 4);

    // q~ B-fragments: B[k=d][n=i], q~ = bf16(qS * kj)
    s16x8 qf[4][2];
#pragma unroll
    for (int nb = 0; nb < 4; ++nb) {
      const float* qp = qh + (i0 + nb * 16 + c) * D_;
      f32x4 a0 = *(const f32x4*)(qp + q * 8);
      f32x4 a1 = *(const f32x4*)(qp + q * 8 + 4);
      f32x4 b0 = *(const f32x4*)(qp + 32 + q * 8);
      f32x4 b1 = *(const f32x4*)(qp + 32 + q * 8 + 4);
      union { unsigned u[4]; s16x8 v; } t0, t1;
      t0.u[0] = pk_bf16(a0.x * kj0a.x, a0.y * kj0a.y);
      t0.u[1] = pk_bf16(a0.z * kj0a.z, a0.w * kj0a.w);
      t0.u[2] = pk_bf16(a1.x * kj0b.x, a1.y * kj0b.y);
      t0.u[3] = pk_bf16(a1.z * kj0b.z, a1.w * kj0b.w);
      t1.u[0] = pk_bf16(b0.x * kj1a.x, b0.y * kj1a.y);
      t1.u[1] = pk_bf16(b0.z * kj1a.z, b0.w * kj1a.w);
      t1.u[2] = pk_bf16(b1.x * kj1b.x, b1.y * kj1b.y);
      t1.u[3] = pk_bf16(b1.z * kj1b.z, b1.w * kj1b.w);
      qf[nb][0] = t0.v;
      qf[nb][1] = t1.v;
    }

    for (int k0 = 0; k0 < N_; k0 += 64) {
#pragma unroll
      for (int mb = 0; mb < 4; ++mb) {
        // S A-frags: pre-cast bf16 kk rows (pure 16B loads)
        const unsigned short* kp = kkh + (k0 + mb * 16 + c) * D_;
        s16x8 ka0 = *(const s16x8*)(kp + q * 8);
        s16x8 ka1 = *(const s16x8*)(kp + 32 + q * 8);
        // PV A-frags: pre-cast bf16 vk^T (pure 8B loads, zero build VALU)
        s16x4 av[4];
#pragma unroll
        for (int md = 0; md < 4; ++md)
          av[md] =
              *(const s16x4*)(vkh + (md * 16 + c) * N_ + k0 + mb * 16 + q * 4);

        f32x4 st[4];
#pragma unroll
        for (int nb = 0; nb < 4; ++nb) {
          f32x4 z = (f32x4){0.f, 0.f, 0.f, 0.f};
          z = mfma32(ka0, qf[nb][0], z);
          z = mfma32(ka1, qf[nb][1], z);
          st[nb] = z;
        }
        s16x4 pn[4];
#pragma unroll
        for (int nb = 0; nb < 4; ++nb) {
          float p0 = __builtin_exp2f(st[nb].x);
          float p1 = __builtin_exp2f(st[nb].y);
          float p2 = __builtin_exp2f(st[nb].z);
          float p3 = __builtin_exp2f(st[nb].w);
          lac[nb] += (p0 + p1) + (p2 + p3);
          union { unsigned u[2]; s16x4 v4; } t;
          t.u[0] = pk_bf16(p0, p1);
          t.u[1] = pk_bf16(p2, p3);
          pn[nb] = t.v4;
        }
        if (jj == 0) {
#pragma unroll
          for (int md = 0; md < 4; ++md)
#pragma unroll
            for (int nb = 0; nb < 4; ++nb)
              accA[md][nb] = mfma16(av[md], pn[nb], accA[md][nb]);
        } else {
#pragma unroll
          for (int md = 0; md < 4; ++md)
#pragma unroll
            for (int nb = 0; nb < 4; ++nb)
              accB[md][nb] = mfma16(av[md], pn[nb], accB[md][nb]);
        }
      }
    }
  }

  // ---- epilogue: yv = acc0*vj0 + acc1*vj1, then cross-wave tree reduce ----
  const int j0 = jc * 8 + wave * 2;
  f32x4 yv[4][4];
#pragma unroll
  for (int md = 0; md < 4; ++md) {
    const f32x4 vs0 = *(const f32x4*)(vjh + j0 * D_ + md * 16 + q * 4);
    const f32x4 vs1 = *(const f32x4*)(vjh + (j0 + 1) * D_ + md * 16 + q * 4);
#pragma unroll
    for (int nb = 0; nb < 4; ++nb)
      yv[md][nb] = accA[md][nb] * vs0 + accB[md][nb] * vs1;
  }

  __shared__ float red[2][64 * 68];  // 34.8 KB
  __shared__ float lredA[2][64];
  __shared__ float lredB[64];

  float lv[4];
#pragma unroll
  for (int nb = 0; nb < 4; ++nb) {
    float v = lac[nb];
    v += __shfl_xor(v, 16);
    v += __shfl_xor(v, 32);
    lv[nb] = v;  // valid at q==0 lanes
  }

  if (wave >= 2) {
    float* dst = red[wave - 2];
#pragma unroll
    for (int mb = 0; mb < 4; ++mb)
#pragma unroll
      for (int nb = 0; nb < 4; ++nb)
        *(f32x4*)&dst[(nb * 16 + c) * 68 + mb * 16 + q * 4] = yv[mb][nb];
    if (q == 0)
#pragma unroll
      for (int nb = 0; nb < 4; ++nb) lredA[wave - 2][nb * 16 + c] = lv[nb];
  }
  __syncthreads();
  if (wave < 2) {
    const float* src = red[wave];
#pragma unroll
    for (int mb = 0; mb < 4; ++mb)
#pragma unroll
      for (int nb = 0; nb < 4; ++nb)
        yv[mb][nb] += *(const f32x4*)&src[(nb * 16 + c) * 68 + mb * 16 + q * 4];
    if (q == 0)
#pragma unroll
      for (int nb = 0; nb < 4; ++nb) lv[nb] += lredA[wave][nb * 16 + c];
  }
  __syncthreads();
  if (wave == 1) {
#pragma unroll
    for (int mb = 0; mb < 4; ++mb)
#pragma unroll
      for (int nb = 0; nb < 4; ++nb)
        *(f32x4*)&red[0][(nb * 16 + c) * 68 + mb * 16 + q * 4] = yv[mb][nb];
    if (q == 0)
#pragma unroll
      for (int nb = 0; nb < 4; ++nb) lredB[nb * 16 + c] = lv[nb];
  }
  __syncthreads();
  if (wave == 0) {
    float* out = slab + ((h * 32 + jc) * 4 + ic) * 4096;
#pragma unroll
    for (int mb = 0; mb < 4; ++mb)
#pragma unroll
      for (int nb = 0; nb < 4; ++nb) {
        f32x4 v = yv[mb][nb] +
                  *(const f32x4*)&red[0][(nb * 16 + c) * 68 + mb * 16 + q * 4];
        *(f32x4*)(out + (nb * 16 + c) * 64 + mb * 16 + q * 4) = v;
      }
    if (q == 0)
#pragma unroll
      for (int nb = 0; nb < 4; ++nb)
        lslab[(h * 32 + jc) * 256 + ic * 64 + nb * 16 + c] =
            lv[nb] + lredB[nb * 16 + c];
  }
}

// ---------------------------------------------------------------------------
// Kernel 3: reduce 32 j-chunk partials, normalize, head re-interleave.
// Vectorized f32x4: 32768 threads = 128 blocks.
// ---------------------------------------------------------------------------
__global__ __launch_bounds__(256) void reduce_kernel(
    const float* __restrict__ slab, const float* __restrict__ lslab,
    float* __restrict__ yn) {
  int idx = blockIdx.x * 256 + threadIdx.x;  // 32768 = 8h*4ic*64il*16dg
  int h = idx >> 12;
  int r = idx & 4095;
  int ic = r >> 10;
  int il = (r >> 4) & 63;
  int d4 = (r & 15) * 4;
  f32x4 s = {0.f, 0.f, 0.f, 0.f};
  float l = 0.f;
#pragma unroll 4
  for (int jc = 0; jc < 32; ++jc) {
    s += *(const f32x4*)&slab[(((h * 32 + jc) * 4 + ic) << 12) + il * 64 + d4];
    l += lslab[(h * 32 + jc) * 256 + ic * 64 + il];
  }
  int i = ic * 64 + il;
  float rl = 1.f / l;
  f32x4 o = {s.x * rl, s.y * rl, s.z * rl, s.w * rl};
  *(f32x4*)&yn[i * C_ + h * 64 + d4] = o;
}

// ---------------------------------------------------------------------------
// Kernel 4: out = yn[256,512] @ W_out[512,512] + b_out
// BM=16, BN=64, BK=32; grid (8,16) = 128 blocks.
// ---------------------------------------------------------------------------
__global__ __launch_bounds__(256) void out_gemm(
    const float* __restrict__ A, const float* __restrict__ W,
    const float* __restrict__ b, float* __restrict__ out) {
  __shared__ float As[32][17];
  __shared__ float Bs[32][68];
  const int bx = blockIdx.x;
  const int by = blockIdx.y;
  const int tid = threadIdx.x;
  const int m = tid >> 4;
  const int c4 = (tid & 15) * 4;
  float acc0 = 0.f, acc1 = 0.f, acc2 = 0.f, acc3 = 0.f;

  const int lk = tid & 31;
  const int lm = tid >> 5;
  const int bk = tid >> 4;

  for (int k0 = 0; k0 < C_; k0 += 32) {
    As[lk][lm] = A[(by * 16 + lm) * C_ + k0 + lk];
    As[lk][lm + 8] = A[(by * 16 + lm + 8) * C_ + k0 + lk];
    *(f32x4*)&Bs[bk][c4] = *(const f32x4*)&W[(k0 + bk) * C_ + bx * 64 + c4];
    *(f32x4*)&Bs[bk + 16][c4] =
        *(const f32x4*)&W[(k0 + bk + 16) * C_ + bx * 64 + c4];
    __syncthreads();
#pragma unroll
    for (int kq = 0; kq < 32; ++kq) {
      float a = As[kq][m];
      f32x4 bv = *(const f32x4*)&Bs[kq][c4];
      acc0 += a * bv.x; acc1 += a * bv.y; acc2 += a * bv.z; acc3 += a * bv.w;
    }
    __syncthreads();
  }

  const int i = by * 16 + m;
  const int col = bx * 64 + c4;
  f32x4 o = {acc0 + b[col + 0], acc1 + b[col + 1], acc2 + b[col + 2],
             acc3 + b[col + 3]};
  *(f32x4*)(out + i * C_ + col) = o;
}

// ---------------------------------------------------------------------------
extern "C" void kernel_launch(void* const* d_in, const int* in_sizes, int n_in,
                              void* d_out, int out_size, void* d_ws,
                              size_t ws_size, hipStream_t stream) {
  const float* x     = (const float*)d_in[0];
  const float* W_att = (const float*)d_in[1];
  const float* b_att = (const float*)d_in[2];
  const float* W_out = (const float*)d_in[3];
  const float* b_out = (const float*)d_in[4];

  char* ws = (char*)d_ws;
  float* slab           = (float*)(ws + 0);         // 16777216 B
  float* lslab          = (float*)(ws + 16777216);  //   262144 B
  float* qSb            = (float*)(ws + 17039360);  //   524288 B
  float* kj             = (float*)(ws + 17563648);  //   524288 B
  unsigned short* kkB   = (unsigned short*)(ws + 18087936);  // 262144 B
  float* vj             = (float*)(ws + 18350080);  //   524288 B
  unsigned short* vkBT  = (unsigned short*)(ws + 18874368);  // 262144 B
  float* yn             = (float*)(ws + 19398656);  //   524288 B

  proj_kernel<<<dim3(40, 16), 256, 0, stream>>>(x, W_att, b_att, qSb, kj, kkB,
                                                vj, vkBT);
  flash3_kernel<<<dim3(32, 4, 8), 256, 0, stream>>>(qSb, kj, kkB, vj, vkBT,
                                                    slab, lslab);
  reduce_kernel<<<dim3(128), 256, 0, stream>>>(slab, lslab, yn);
  out_gemm<<<dim3(8, 16), 256, 0, stream>>>(yn, W_out, b_out, (float*)d_out);
}

// Round 12
// 210.258 us; speedup vs baseline: 2.2092x; 2.2092x over previous
//
#include <hip/hip_runtime.h>
#include <stdint.h>

// ---------------------------------------------------------------------------
// ThirdOrderAttention: B=1, N=256, C=512, H=8, D=64
// Flash attention over virtual L=65536 KV (K'=kj*kk, V'=vj*vk), bf16 MFMA.
// R12: R9 verbatim (the proven 126.6us flash3: 256 thr, (256,2), flat
// 32-slice stream, AGPR acc untouched until one epilogue) + softmax
// denominator moved to the matrix pipe: l = ones @ P^T via one extra mfma16
// per nb-slice (constant all-ones A-frag). Deletes 16 lac-VALU/slice and the
// epilogue shuffles. +16 AGPR (208 <= 256 unified budget; R11's 280 spilled).
// ---------------------------------------------------------------------------

typedef __attribute__((ext_vector_type(4))) float f32x4;
typedef __attribute__((ext_vector_type(4))) short s16x4;
typedef __attribute__((ext_vector_type(8))) short s16x8;

#define H_ 8
#define N_ 256
#define D_ 64
#define C_ 512
#define NC5 2560
#define SCALE_LOG2E 0.1803368801111204f  // 0.125 * log2(e): P = exp2(S')

// ----- bf16 helpers --------------------------------------------------------
__device__ __forceinline__ unsigned short f2bf_rne(float x) {
  union { float f; unsigned u; } a; a.f = x;
  unsigned r = a.u + 0x7fffu + ((a.u >> 16) & 1u);
  return (unsigned short)(r >> 16);
}

__device__ __forceinline__ unsigned pk_bf16(float a, float b) {
#if __has_builtin(__builtin_amdgcn_cvt_pk_bf16_f32)
  typedef __attribute__((ext_vector_type(2))) __bf16 bf16x2;
  union { bf16x2 v; unsigned u; } u;
  u.v = __builtin_amdgcn_cvt_pk_bf16_f32(a, b);
  return u.u;
#else
  return (unsigned)f2bf_rne(a) | ((unsigned)f2bf_rne(b) << 16);
#endif
}

// ----- MFMA wrappers -------------------------------------------------------
__device__ __forceinline__ f32x4 mfma32(s16x8 a, s16x8 b, f32x4 c) {
  return __builtin_amdgcn_mfma_f32_16x16x32_bf16(a, b, c, 0, 0, 0);
}

__device__ __forceinline__ f32x4 mfma16(s16x4 a, s16x4 b, f32x4 c) {
#if __has_builtin(__builtin_amdgcn_mfma_f32_16x16x16bf16_1k)
  return __builtin_amdgcn_mfma_f32_16x16x16bf16_1k(a, b, c, 0, 0, 0);
#else
  asm volatile("s_nop 1\n\t"
               "v_mfma_f32_16x16x16_bf16 %0, %1, %2, %0\n\t"
               "s_nop 7\n\t"
               "s_nop 2"
               : "+v"(c) : "v"(a), "v"(b));
  return c;
#endif
}

// ---------------------------------------------------------------------------
// Kernel 1: projection GEMM  p = x[256,512] @ W_att[512,2560] + b_att
// BM=16, BN=64, BK=32; 256 threads; 1x4 micro-tile. Grid (40, 16) = 640 blks.
// Epilogue: qS f32 (pre-scaled), kj f32, kk bf16, vj f32, vkT f32.  [R9]
// ---------------------------------------------------------------------------
__global__ __launch_bounds__(256) void proj_kernel(
    const float* __restrict__ x, const float* __restrict__ W,
    const float* __restrict__ b,
    float* __restrict__ qS, float* __restrict__ kj,
    unsigned short* __restrict__ kkB, float* __restrict__ vj,
    float* __restrict__ vkT) {
  __shared__ float As[32][17];
  __shared__ float Bs[32][68];
  const int bx = blockIdx.x;  // 40 col tiles of 64
  const int by = blockIdx.y;  // 16 row tiles of 16
  const int tid = threadIdx.x;
  const int m = tid >> 4;        // 0..15 output row
  const int c4 = (tid & 15) * 4; // output col group
  float acc0 = 0.f, acc1 = 0.f, acc2 = 0.f, acc3 = 0.f;

  const int lk = tid & 31;   // A-load k
  const int lm = tid >> 5;   // A-load m (0..7), +8 second half
  const int bk = tid >> 4;   // B-load k (0..15), +16 second half

  for (int k0 = 0; k0 < C_; k0 += 32) {
    As[lk][lm] = x[(by * 16 + lm) * C_ + k0 + lk];
    As[lk][lm + 8] = x[(by * 16 + lm + 8) * C_ + k0 + lk];
    *(f32x4*)&Bs[bk][c4] = *(const f32x4*)&W[(k0 + bk) * NC5 + bx * 64 + c4];
    *(f32x4*)&Bs[bk + 16][c4] =
        *(const f32x4*)&W[(k0 + bk + 16) * NC5 + bx * 64 + c4];
    __syncthreads();
#pragma unroll
    for (int kq = 0; kq < 32; ++kq) {
      float a = As[kq][m];
      f32x4 bv = *(const f32x4*)&Bs[kq][c4];
      acc0 += a * bv.x; acc1 += a * bv.y; acc2 += a * bv.z; acc3 += a * bv.w;
    }
    __syncthreads();
  }

  const int i = by * 16 + m;
  const int col0 = bx * 64 + c4;
  const int h = (bx * 64) / 320;
  const int part = ((bx * 64) % 320) >> 6;
  const int d0 = c4;
  float v0 = acc0 + b[col0 + 0];
  float v1 = acc1 + b[col0 + 1];
  float v2 = acc2 + b[col0 + 2];
  float v3 = acc3 + b[col0 + 3];
  const int idx = (h * N_ + i) * D_ + d0;
  if (part == 0) {
    f32x4 o = {v0 * SCALE_LOG2E, v1 * SCALE_LOG2E, v2 * SCALE_LOG2E,
               v3 * SCALE_LOG2E};
    *(f32x4*)(qS + idx) = o;
  } else if (part == 1) {
    f32x4 o = {v0, v1, v2, v3};
    *(f32x4*)(kj + idx) = o;
  } else if (part == 2) {
    union { unsigned u[2]; s16x4 v4; } t;
    t.u[0] = pk_bf16(v0, v1);
    t.u[1] = pk_bf16(v2, v3);
    *(s16x4*)(kkB + idx) = t.v4;
  } else if (part == 3) {
    f32x4 o = {v0, v1, v2, v3};
    *(f32x4*)(vj + idx) = o;
  } else {
    vkT[(h * D_ + d0 + 0) * N_ + i] = v0;
    vkT[(h * D_ + d0 + 1) * N_ + i] = v1;
    vkT[(h * D_ + d0 + 2) * N_ + i] = v2;
    vkT[(h * D_ + d0 + 3) * N_ + i] = v3;
  }
}

// ---------------------------------------------------------------------------
// Kernel 2: fused third-order flash attention (R9 + MFMA-computed l).
// Grid (32 jc, 4 ic, 8 h) = 1024 blocks x 256 thr; wave owns 2 j, 64 i.
// Per (k0, 16-t slice): S^T = kk_bf16 . q~ (q~ = bf16(qS*kj)); P = exp2(S');
// S^T C-layout == mfma16 B-layout -> Y^T += F @ P^T (F = bf16(vj*vkT)) and
// l += ones @ P^T (constant A-frag; matrix pipe, zero VALU).
// acc/accL AGPR-resident until the single tree-reduce epilogue.
// ---------------------------------------------------------------------------
__global__ __launch_bounds__(256, 2) void flash3_kernel(
    const float* __restrict__ qS,           // [H][N][D] f32, pre-scaled
    const float* __restrict__ kjF,          // [H][N][D] f32
    const unsigned short* __restrict__ kkB, // [H][N][D] bf16
    const float* __restrict__ vjF,          // [H][N][D] f32
    const float* __restrict__ vkT,          // [H][D][N] f32
    float* __restrict__ slab,               // [H][32][4][64][64]
    float* __restrict__ lslab) {            // [H][32][256]
  const int jc = blockIdx.x;
  const int ic = blockIdx.y;
  const int h = blockIdx.z;
  const int wave = threadIdx.x >> 6;
  const int lane = threadIdx.x & 63;
  const int q = lane >> 4;
  const int c = lane & 15;
  const int i0 = ic * 64;

  const float* qh = qS + h * (N_ * D_);
  const float* kjh = kjF + h * (N_ * D_);
  const unsigned short* kkh = kkB + h * (N_ * D_);
  const float* vjh = vjF + h * (N_ * D_);
  const float* vkh = vkT + h * (D_ * N_);

  f32x4 acc[4][4];  // Y^T tiles: [mb_d][nb over i]
#pragma unroll
  for (int mb = 0; mb < 4; ++mb)
#pragma unroll
    for (int nb = 0; nb < 4; ++nb) acc[mb][nb] = (f32x4){0.f, 0.f, 0.f, 0.f};
  f32x4 accL[4];  // l partials: every row of C holds l[i=nb*16+c]
#pragma unroll
  for (int nb = 0; nb < 4; ++nb) accL[nb] = (f32x4){0.f, 0.f, 0.f, 0.f};

  // constant all-ones bf16 A-fragment (1.0bf16 = 0x3F80)
  union { unsigned u[2]; s16x4 v4; } onesu;
  onesu.u[0] = 0x3F803F80u;
  onesu.u[1] = 0x3F803F80u;
  const s16x4 ones = onesu.v4;

  for (int jj = 0; jj < 2; ++jj) {
    const int j = jc * 8 + wave * 2 + jj;
    const f32x4 kj0a = *(const f32x4*)(kjh + j * D_ + q * 8);
    const f32x4 kj0b = *(const f32x4*)(kjh + j * D_ + q * 8 + 4);
    const f32x4 kj1a = *(const f32x4*)(kjh + j * D_ + 32 + q * 8);
    const f32x4 kj1b = *(const f32x4*)(kjh + j * D_ + 32 + q * 8 + 4);
    float vjv[4];
#pragma unroll
    for (int mb = 0; mb < 4; ++mb) vjv[mb] = vjh[j * D_ + mb * 16 + c];

    // q~ B-fragments: B[k=d][n=i], q~ = bf16(qS * kj)
    s16x8 qf[4][2];
#pragma unroll
    for (int nb = 0; nb < 4; ++nb) {
      const float* qp = qh + (i0 + nb * 16 + c) * D_;
      f32x4 a0 = *(const f32x4*)(qp + q * 8);
      f32x4 a1 = *(const f32x4*)(qp + q * 8 + 4);
      f32x4 b0 = *(const f32x4*)(qp + 32 + q * 8);
      f32x4 b1 = *(const f32x4*)(qp + 32 + q * 8 + 4);
      union { unsigned u[4]; s16x8 v; } t0, t1;
      t0.u[0] = pk_bf16(a0.x * kj0a.x, a0.y * kj0a.y);
      t0.u[1] = pk_bf16(a0.z * kj0a.z, a0.w * kj0a.w);
      t0.u[2] = pk_bf16(a1.x * kj0b.x, a1.y * kj0b.y);
      t0.u[3] = pk_bf16(a1.z * kj0b.z, a1.w * kj0b.w);
      t1.u[0] = pk_bf16(b0.x * kj1a.x, b0.y * kj1a.y);
      t1.u[1] = pk_bf16(b0.z * kj1a.z, b0.w * kj1a.w);
      t1.u[2] = pk_bf16(b1.x * kj1b.x, b1.y * kj1b.y);
      t1.u[3] = pk_bf16(b1.z * kj1b.z, b1.w * kj1b.w);
      qf[nb][0] = t0.v;
      qf[nb][1] = t1.v;
    }

    for (int k0 = 0; k0 < N_; k0 += 64) {
#pragma unroll
      for (int mb = 0; mb < 4; ++mb) {
        // A-frags for S: pre-cast bf16 kk rows (pure loads, no VALU)
        const unsigned short* kp = kkh + (k0 + mb * 16 + c) * D_;
        s16x8 ka0 = *(const s16x8*)(kp + q * 8);
        s16x8 ka1 = *(const s16x8*)(kp + 32 + q * 8);
        // F loads issued early (latency overlap with MFMA/exp)
        f32x4 fv[4];
#pragma unroll
        for (int md = 0; md < 4; ++md)
          fv[md] =
              *(const f32x4*)(vkh + (md * 16 + c) * N_ + k0 + mb * 16 + q * 4);

        f32x4 st[4];
#pragma unroll
        for (int nb = 0; nb < 4; ++nb) {
          f32x4 z = (f32x4){0.f, 0.f, 0.f, 0.f};
          z = mfma32(ka0, qf[nb][0], z);
          z = mfma32(ka1, qf[nb][1], z);
          st[nb] = z;
        }
        s16x4 pn[4];
#pragma unroll
        for (int nb = 0; nb < 4; ++nb) {
          float p0 = __builtin_exp2f(st[nb].x);
          float p1 = __builtin_exp2f(st[nb].y);
          float p2 = __builtin_exp2f(st[nb].z);
          float p3 = __builtin_exp2f(st[nb].w);
          union { unsigned u[2]; s16x4 v4; } t;
          t.u[0] = pk_bf16(p0, p1);
          t.u[1] = pk_bf16(p2, p3);
          pn[nb] = t.v4;
        }
        // l accumulation on the matrix pipe: l += ones @ P^T
#pragma unroll
        for (int nb = 0; nb < 4; ++nb)
          accL[nb] = mfma16(ones, pn[nb], accL[nb]);
        // PV slice: K=16 over this t-slice
#pragma unroll
        for (int md = 0; md < 4; ++md) {
          float s = vjv[md];
          union { unsigned u[2]; s16x4 v4; } t;
          t.u[0] = pk_bf16(fv[md].x * s, fv[md].y * s);
          t.u[1] = pk_bf16(fv[md].z * s, fv[md].w * s);
#pragma unroll
          for (int nb = 0; nb < 4; ++nb)
            acc[md][nb] = mfma16(t.v4, pn[nb], acc[md][nb]);
        }
      }
    }
  }

  // ---- epilogue: cross-wave tree reduce (stride 68 kills bank conflicts) --
  __shared__ float red[2][64 * 68];  // 34.8 KB
  __shared__ float lredA[2][64];
  __shared__ float lredB[64];

  float lv[4];
#pragma unroll
  for (int nb = 0; nb < 4; ++nb) lv[nb] = accL[nb].x;  // all rows identical

  if (wave >= 2) {
    float* dst = red[wave - 2];
#pragma unroll
    for (int mb = 0; mb < 4; ++mb)
#pragma unroll
      for (int nb = 0; nb < 4; ++nb)
        *(f32x4*)&dst[(nb * 16 + c) * 68 + mb * 16 + q * 4] = acc[mb][nb];
    if (q == 0)
#pragma unroll
      for (int nb = 0; nb < 4; ++nb) lredA[wave - 2][nb * 16 + c] = lv[nb];
  }
  __syncthreads();
  if (wave < 2) {
    const float* src = red[wave];
#pragma unroll
    for (int mb = 0; mb < 4; ++mb)
#pragma unroll
      for (int nb = 0; nb < 4; ++nb)
        acc[mb][nb] += *(const f32x4*)&src[(nb * 16 + c) * 68 + mb * 16 + q * 4];
    if (q == 0)
#pragma unroll
      for (int nb = 0; nb < 4; ++nb) lv[nb] += lredA[wave][nb * 16 + c];
  }
  __syncthreads();
  if (wave == 1) {
#pragma unroll
    for (int mb = 0; mb < 4; ++mb)
#pragma unroll
      for (int nb = 0; nb < 4; ++nb)
        *(f32x4*)&red[0][(nb * 16 + c) * 68 + mb * 16 + q * 4] = acc[mb][nb];
    if (q == 0)
#pragma unroll
      for (int nb = 0; nb < 4; ++nb) lredB[nb * 16 + c] = lv[nb];
  }
  __syncthreads();
  if (wave == 0) {
    float* out = slab + ((h * 32 + jc) * 4 + ic) * 4096;
#pragma unroll
    for (int mb = 0; mb < 4; ++mb)
#pragma unroll
      for (int nb = 0; nb < 4; ++nb) {
        f32x4 v = acc[mb][nb] +
                  *(const f32x4*)&red[0][(nb * 16 + c) * 68 + mb * 16 + q * 4];
        *(f32x4*)(out + (nb * 16 + c) * 64 + mb * 16 + q * 4) = v;
      }
    if (q == 0)
#pragma unroll
      for (int nb = 0; nb < 4; ++nb)
        lslab[(h * 32 + jc) * 256 + ic * 64 + nb * 16 + c] =
            lv[nb] + lredB[nb * 16 + c];
  }
}

// ---------------------------------------------------------------------------
// Kernel 3: reduce 32 j-chunk partials, normalize, head re-interleave.
// Vectorized f32x4: 32768 threads = 128 blocks.
// ---------------------------------------------------------------------------
__global__ __launch_bounds__(256) void reduce_kernel(
    const float* __restrict__ slab, const float* __restrict__ lslab,
    float* __restrict__ yn) {
  int idx = blockIdx.x * 256 + threadIdx.x;  // 32768 = 8h*4ic*64il*16dg
  int h = idx >> 12;
  int r = idx & 4095;
  int ic = r >> 10;
  int il = (r >> 4) & 63;
  int d4 = (r & 15) * 4;
  f32x4 s = {0.f, 0.f, 0.f, 0.f};
  float l = 0.f;
#pragma unroll 4
  for (int jc = 0; jc < 32; ++jc) {
    s += *(const f32x4*)&slab[(((h * 32 + jc) * 4 + ic) << 12) + il * 64 + d4];
    l += lslab[(h * 32 + jc) * 256 + ic * 64 + il];
  }
  int i = ic * 64 + il;
  float rl = 1.f / l;
  f32x4 o = {s.x * rl, s.y * rl, s.z * rl, s.w * rl};
  *(f32x4*)&yn[i * C_ + h * 64 + d4] = o;
}

// ---------------------------------------------------------------------------
// Kernel 4: out = yn[256,512] @ W_out[512,512] + b_out
// BM=16, BN=64, BK=32; grid (8,16) = 128 blocks.
// ---------------------------------------------------------------------------
__global__ __launch_bounds__(256) void out_gemm(
    const float* __restrict__ A, const float* __restrict__ W,
    const float* __restrict__ b, float* __restrict__ out) {
  __shared__ float As[32][17];
  __shared__ float Bs[32][68];
  const int bx = blockIdx.x;
  const int by = blockIdx.y;
  const int tid = threadIdx.x;
  const int m = tid >> 4;
  const int c4 = (tid & 15) * 4;
  float acc0 = 0.f, acc1 = 0.f, acc2 = 0.f, acc3 = 0.f;

  const int lk = tid & 31;
  const int lm = tid >> 5;
  const int bk = tid >> 4;

  for (int k0 = 0; k0 < C_; k0 += 32) {
    As[lk][lm] = A[(by * 16 + lm) * C_ + k0 + lk];
    As[lk][lm + 8] = A[(by * 16 + lm + 8) * C_ + k0 + lk];
    *(f32x4*)&Bs[bk][c4] = *(const f32x4*)&W[(k0 + bk) * C_ + bx * 64 + c4];
    *(f32x4*)&Bs[bk + 16][c4] =
        *(const f32x4*)&W[(k0 + bk + 16) * C_ + bx * 64 + c4];
    __syncthreads();
#pragma unroll
    for (int kq = 0; kq < 32; ++kq) {
      float a = As[kq][m];
      f32x4 bv = *(const f32x4*)&Bs[kq][c4];
      acc0 += a * bv.x; acc1 += a * bv.y; acc2 += a * bv.z; acc3 += a * bv.w;
    }
    __syncthreads();
  }

  const int i = by * 16 + m;
  const int col = bx * 64 + c4;
  f32x4 o = {acc0 + b[col + 0], acc1 + b[col + 1], acc2 + b[col + 2],
             acc3 + b[col + 3]};
  *(f32x4*)(out + i * C_ + col) = o;
}

// ---------------------------------------------------------------------------
extern "C" void kernel_launch(void* const* d_in, const int* in_sizes, int n_in,
                              void* d_out, int out_size, void* d_ws,
                              size_t ws_size, hipStream_t stream) {
  const float* x     = (const float*)d_in[0];
  const float* W_att = (const float*)d_in[1];
  const float* b_att = (const float*)d_in[2];
  const float* W_out = (const float*)d_in[3];
  const float* b_out = (const float*)d_in[4];

  char* ws = (char*)d_ws;
  float* slab           = (float*)(ws + 0);         // 16777216 B
  float* lslab          = (float*)(ws + 16777216);  //   262144 B
  float* qSb            = (float*)(ws + 17039360);  //   524288 B
  float* kj             = (float*)(ws + 17563648);  //   524288 B
  unsigned short* kkB   = (unsigned short*)(ws + 18087936);  // 262144 B
  float* vj             = (float*)(ws + 18350080);  //   524288 B
  float* vkT            = (float*)(ws + 18874368);  //   524288 B
  float* yn             = (float*)(ws + 19398656);  //   524288 B

  proj_kernel<<<dim3(40, 16), 256, 0, stream>>>(x, W_att, b_att, qSb, kj, kkB,
                                                vj, vkT);
  flash3_kernel<<<dim3(32, 4, 8), 256, 0, stream>>>(qSb, kj, kkB, vj, vkT,
                                                    slab, lslab);
  reduce_kernel<<<dim3(128), 256, 0, stream>>>(slab, lslab, yn);
  out_gemm<<<dim3(8, 16), 256, 0, stream>>>(yn, W_out, b_out, (float*)d_out);
}

// Round 13
// 205.969 us; speedup vs baseline: 2.2552x; 1.0208x over previous
//
#include <hip/hip_runtime.h>
#include <stdint.h>

// ---------------------------------------------------------------------------
// ThirdOrderAttention: B=1, N=256, C=512, H=8, D=64
// Flash attention over virtual L=65536 KV (K'=kj*kk, V'=vj*vk), bf16 MFMA.
// R13: flash3 + reduce FROZEN from R12 (210us champion; flash3 at its
// structural floor). Aux fixes only: register-prefetch double-buffering in
// proj/out_gemm k-loops (hide global latency behind the FMA block) and an
// LDS transpose for proj's vkT store (f32x4 instead of scalar scatter).
// ---------------------------------------------------------------------------

typedef __attribute__((ext_vector_type(4))) float f32x4;
typedef __attribute__((ext_vector_type(4))) short s16x4;
typedef __attribute__((ext_vector_type(8))) short s16x8;

#define H_ 8
#define N_ 256
#define D_ 64
#define C_ 512
#define NC5 2560
#define SCALE_LOG2E 0.1803368801111204f  // 0.125 * log2(e): P = exp2(S')

// ----- bf16 helpers --------------------------------------------------------
__device__ __forceinline__ unsigned short f2bf_rne(float x) {
  union { float f; unsigned u; } a; a.f = x;
  unsigned r = a.u + 0x7fffu + ((a.u >> 16) & 1u);
  return (unsigned short)(r >> 16);
}

__device__ __forceinline__ unsigned pk_bf16(float a, float b) {
#if __has_builtin(__builtin_amdgcn_cvt_pk_bf16_f32)
  typedef __attribute__((ext_vector_type(2))) __bf16 bf16x2;
  union { bf16x2 v; unsigned u; } u;
  u.v = __builtin_amdgcn_cvt_pk_bf16_f32(a, b);
  return u.u;
#else
  return (unsigned)f2bf_rne(a) | ((unsigned)f2bf_rne(b) << 16);
#endif
}

// ----- MFMA wrappers -------------------------------------------------------
__device__ __forceinline__ f32x4 mfma32(s16x8 a, s16x8 b, f32x4 c) {
  return __builtin_amdgcn_mfma_f32_16x16x32_bf16(a, b, c, 0, 0, 0);
}

__device__ __forceinline__ f32x4 mfma16(s16x4 a, s16x4 b, f32x4 c) {
#if __has_builtin(__builtin_amdgcn_mfma_f32_16x16x16bf16_1k)
  return __builtin_amdgcn_mfma_f32_16x16x16bf16_1k(a, b, c, 0, 0, 0);
#else
  asm volatile("s_nop 1\n\t"
               "v_mfma_f32_16x16x16_bf16 %0, %1, %2, %0\n\t"
               "s_nop 7\n\t"
               "s_nop 2"
               : "+v"(c) : "v"(a), "v"(b));
  return c;
#endif
}

// ---------------------------------------------------------------------------
// Kernel 1: projection GEMM  p = x[256,512] @ W_att[512,2560] + b_att
// BM=16, BN=64, BK=32; 256 threads; grid (40,16)=640 blocks.
// R13: register-prefetch double-buffered k-loop; vkT store via LDS transpose.
// Epilogue: qS f32 (pre-scaled), kj f32, kk bf16, vj f32, vkT f32.
// ---------------------------------------------------------------------------
__global__ __launch_bounds__(256) void proj_kernel(
    const float* __restrict__ x, const float* __restrict__ W,
    const float* __restrict__ b,
    float* __restrict__ qS, float* __restrict__ kj,
    unsigned short* __restrict__ kkB, float* __restrict__ vj,
    float* __restrict__ vkT) {
  __shared__ float As[32][17];
  __shared__ float Bs[32][68];
  const int bx = blockIdx.x;  // 40 col tiles of 64
  const int by = blockIdx.y;  // 16 row tiles of 16
  const int tid = threadIdx.x;
  const int m = tid >> 4;        // 0..15 output row
  const int c4 = (tid & 15) * 4; // output col group
  float acc0 = 0.f, acc1 = 0.f, acc2 = 0.f, acc3 = 0.f;

  const int lk = tid & 31;   // A-load k
  const int lm = tid >> 5;   // A-load m (0..7), +8 second half
  const int bk = tid >> 4;   // B-load k (0..15), +16 second half

  // prefetch tile 0 into registers
  float a0r = x[(by * 16 + lm) * C_ + lk];
  float a1r = x[(by * 16 + lm + 8) * C_ + lk];
  f32x4 b0r = *(const f32x4*)&W[bk * NC5 + bx * 64 + c4];
  f32x4 b1r = *(const f32x4*)&W[(bk + 16) * NC5 + bx * 64 + c4];

  for (int k0 = 0; k0 < C_; k0 += 32) {
    As[lk][lm] = a0r;
    As[lk][lm + 8] = a1r;
    *(f32x4*)&Bs[bk][c4] = b0r;
    *(f32x4*)&Bs[bk + 16][c4] = b1r;
    __syncthreads();
    if (k0 + 32 < C_) {  // prefetch next tile; waitcnt lands next iteration
      a0r = x[(by * 16 + lm) * C_ + k0 + 32 + lk];
      a1r = x[(by * 16 + lm + 8) * C_ + k0 + 32 + lk];
      b0r = *(const f32x4*)&W[(k0 + 32 + bk) * NC5 + bx * 64 + c4];
      b1r = *(const f32x4*)&W[(k0 + 32 + bk + 16) * NC5 + bx * 64 + c4];
    }
#pragma unroll
    for (int kq = 0; kq < 32; ++kq) {
      float a = As[kq][m];
      f32x4 bv = *(const f32x4*)&Bs[kq][c4];
      acc0 += a * bv.x; acc1 += a * bv.y; acc2 += a * bv.z; acc3 += a * bv.w;
    }
    __syncthreads();
  }

  const int i = by * 16 + m;
  const int col0 = bx * 64 + c4;
  const int h = (bx * 64) / 320;
  const int part = ((bx * 64) % 320) >> 6;
  const int d0 = c4;
  float v0 = acc0 + b[col0 + 0];
  float v1 = acc1 + b[col0 + 1];
  float v2 = acc2 + b[col0 + 2];
  float v3 = acc3 + b[col0 + 3];
  const int idx = (h * N_ + i) * D_ + d0;
  if (part == 0) {
    f32x4 o = {v0 * SCALE_LOG2E, v1 * SCALE_LOG2E, v2 * SCALE_LOG2E,
               v3 * SCALE_LOG2E};
    *(f32x4*)(qS + idx) = o;
  } else if (part == 1) {
    f32x4 o = {v0, v1, v2, v3};
    *(f32x4*)(kj + idx) = o;
  } else if (part == 2) {
    union { unsigned u[2]; s16x4 v4; } t;
    t.u[0] = pk_bf16(v0, v1);
    t.u[1] = pk_bf16(v2, v3);
    *(s16x4*)(kkB + idx) = t.v4;
  } else if (part == 3) {
    f32x4 o = {v0, v1, v2, v3};
    *(f32x4*)(vj + idx) = o;
  } else {
    // vkT: LDS transpose (block-uniform branch), then f32x4 stores.
    float* T = &Bs[0][0];  // reuse as [16][68]
    T[m * 68 + d0 + 0] = v0;
    T[m * 68 + d0 + 1] = v1;
    T[m * 68 + d0 + 2] = v2;
    T[m * 68 + d0 + 3] = v3;
    __syncthreads();
    const int dp = tid >> 2;        // 0..63 (d)
    const int ib = (tid & 3) * 4;   // 0,4,8,12 (i offset)
    f32x4 o = {T[(ib + 0) * 68 + dp], T[(ib + 1) * 68 + dp],
               T[(ib + 2) * 68 + dp], T[(ib + 3) * 68 + dp]};
    *(f32x4*)&vkT[(h * D_ + dp) * N_ + by * 16 + ib] = o;
  }
}

// ---------------------------------------------------------------------------
// Kernel 2: fused third-order flash attention (R12 VERBATIM — frozen).
// Grid (32 jc, 4 ic, 8 h) = 1024 blocks x 256 thr; wave owns 2 j, 64 i.
// Per (k0, 16-t slice): S^T = kk_bf16 . q~ (q~ = bf16(qS*kj)); P = exp2(S');
// S^T C-layout == mfma16 B-layout -> Y^T += F @ P^T (F = bf16(vj*vkT)) and
// l += ones @ P^T (constant A-frag; matrix pipe, zero VALU).
// acc/accL AGPR-resident until the single tree-reduce epilogue.
// ---------------------------------------------------------------------------
__global__ __launch_bounds__(256, 2) void flash3_kernel(
    const float* __restrict__ qS,           // [H][N][D] f32, pre-scaled
    const float* __restrict__ kjF,          // [H][N][D] f32
    const unsigned short* __restrict__ kkB, // [H][N][D] bf16
    const float* __restrict__ vjF,          // [H][N][D] f32
    const float* __restrict__ vkT,          // [H][D][N] f32
    float* __restrict__ slab,               // [H][32][4][64][64]
    float* __restrict__ lslab) {            // [H][32][256]
  const int jc = blockIdx.x;
  const int ic = blockIdx.y;
  const int h = blockIdx.z;
  const int wave = threadIdx.x >> 6;
  const int lane = threadIdx.x & 63;
  const int q = lane >> 4;
  const int c = lane & 15;
  const int i0 = ic * 64;

  const float* qh = qS + h * (N_ * D_);
  const float* kjh = kjF + h * (N_ * D_);
  const unsigned short* kkh = kkB + h * (N_ * D_);
  const float* vjh = vjF + h * (N_ * D_);
  const float* vkh = vkT + h * (D_ * N_);

  f32x4 acc[4][4];  // Y^T tiles: [mb_d][nb over i]
#pragma unroll
  for (int mb = 0; mb < 4; ++mb)
#pragma unroll
    for (int nb = 0; nb < 4; ++nb) acc[mb][nb] = (f32x4){0.f, 0.f, 0.f, 0.f};
  f32x4 accL[4];  // l partials: every row of C holds l[i=nb*16+c]
#pragma unroll
  for (int nb = 0; nb < 4; ++nb) accL[nb] = (f32x4){0.f, 0.f, 0.f, 0.f};

  // constant all-ones bf16 A-fragment (1.0bf16 = 0x3F80)
  union { unsigned u[2]; s16x4 v4; } onesu;
  onesu.u[0] = 0x3F803F80u;
  onesu.u[1] = 0x3F803F80u;
  const s16x4 ones = onesu.v4;

  for (int jj = 0; jj < 2; ++jj) {
    const int j = jc * 8 + wave * 2 + jj;
    const f32x4 kj0a = *(const f32x4*)(kjh + j * D_ + q * 8);
    const f32x4 kj0b = *(const f32x4*)(kjh + j * D_ + q * 8 + 4);
    const f32x4 kj1a = *(const f32x4*)(kjh + j * D_ + 32 + q * 8);
    const f32x4 kj1b = *(const f32x4*)(kjh + j * D_ + 32 + q * 8 + 4);
    float vjv[4];
#pragma unroll
    for (int mb = 0; mb < 4; ++mb) vjv[mb] = vjh[j * D_ + mb * 16 + c];

    // q~ B-fragments: B[k=d][n=i], q~ = bf16(qS * kj)
    s16x8 qf[4][2];
#pragma unroll
    for (int nb = 0; nb < 4; ++nb) {
      const float* qp = qh + (i0 + nb * 16 + c) * D_;
      f32x4 a0 = *(const f32x4*)(qp + q * 8);
      f32x4 a1 = *(const f32x4*)(qp + q * 8 + 4);
      f32x4 b0 = *(const f32x4*)(qp + 32 + q * 8);
      f32x4 b1 = *(const f32x4*)(qp + 32 + q * 8 + 4);
      union { unsigned u[4]; s16x8 v; } t0, t1;
      t0.u[0] = pk_bf16(a0.x * kj0a.x, a0.y * kj0a.y);
      t0.u[1] = pk_bf16(a0.z * kj0a.z, a0.w * kj0a.w);
      t0.u[2] = pk_bf16(a1.x * kj0b.x, a1.y * kj0b.y);
      t0.u[3] = pk_bf16(a1.z * kj0b.z, a1.w * kj0b.w);
      t1.u[0] = pk_bf16(b0.x * kj1a.x, b0.y * kj1a.y);
      t1.u[1] = pk_bf16(b0.z * kj1a.z, b0.w * kj1a.w);
      t1.u[2] = pk_bf16(b1.x * kj1b.x, b1.y * kj1b.y);
      t1.u[3] = pk_bf16(b1.z * kj1b.z, b1.w * kj1b.w);
      qf[nb][0] = t0.v;
      qf[nb][1] = t1.v;
    }

    for (int k0 = 0; k0 < N_; k0 += 64) {
#pragma unroll
      for (int mb = 0; mb < 4; ++mb) {
        // A-frags for S: pre-cast bf16 kk rows (pure loads, no VALU)
        const unsigned short* kp = kkh + (k0 + mb * 16 + c) * D_;
        s16x8 ka0 = *(const s16x8*)(kp + q * 8);
        s16x8 ka1 = *(const s16x8*)(kp + 32 + q * 8);
        // F loads issued early (latency overlap with MFMA/exp)
        f32x4 fv[4];
#pragma unroll
        for (int md = 0; md < 4; ++md)
          fv[md] =
              *(const f32x4*)(vkh + (md * 16 + c) * N_ + k0 + mb * 16 + q * 4);

        f32x4 st[4];
#pragma unroll
        for (int nb = 0; nb < 4; ++nb) {
          f32x4 z = (f32x4){0.f, 0.f, 0.f, 0.f};
          z = mfma32(ka0, qf[nb][0], z);
          z = mfma32(ka1, qf[nb][1], z);
          st[nb] = z;
        }
        s16x4 pn[4];
#pragma unroll
        for (int nb = 0; nb < 4; ++nb) {
          float p0 = __builtin_exp2f(st[nb].x);
          float p1 = __builtin_exp2f(st[nb].y);
          float p2 = __builtin_exp2f(st[nb].z);
          float p3 = __builtin_exp2f(st[nb].w);
          union { unsigned u[2]; s16x4 v4; } t;
          t.u[0] = pk_bf16(p0, p1);
          t.u[1] = pk_bf16(p2, p3);
          pn[nb] = t.v4;
        }
        // l accumulation on the matrix pipe: l += ones @ P^T
#pragma unroll
        for (int nb = 0; nb < 4; ++nb)
          accL[nb] = mfma16(ones, pn[nb], accL[nb]);
        // PV slice: K=16 over this t-slice
#pragma unroll
        for (int md = 0; md < 4; ++md) {
          float s = vjv[md];
          union { unsigned u[2]; s16x4 v4; } t;
          t.u[0] = pk_bf16(fv[md].x * s, fv[md].y * s);
          t.u[1] = pk_bf16(fv[md].z * s, fv[md].w * s);
#pragma unroll
          for (int nb = 0; nb < 4; ++nb)
            acc[md][nb] = mfma16(t.v4, pn[nb], acc[md][nb]);
        }
      }
    }
  }

  // ---- epilogue: cross-wave tree reduce (stride 68 kills bank conflicts) --
  __shared__ float red[2][64 * 68];  // 34.8 KB
  __shared__ float lredA[2][64];
  __shared__ float lredB[64];

  float lv[4];
#pragma unroll
  for (int nb = 0; nb < 4; ++nb) lv[nb] = accL[nb].x;  // all rows identical

  if (wave >= 2) {
    float* dst = red[wave - 2];
#pragma unroll
    for (int mb = 0; mb < 4; ++mb)
#pragma unroll
      for (int nb = 0; nb < 4; ++nb)
        *(f32x4*)&dst[(nb * 16 + c) * 68 + mb * 16 + q * 4] = acc[mb][nb];
    if (q == 0)
#pragma unroll
      for (int nb = 0; nb < 4; ++nb) lredA[wave - 2][nb * 16 + c] = lv[nb];
  }
  __syncthreads();
  if (wave < 2) {
    const float* src = red[wave];
#pragma unroll
    for (int mb = 0; mb < 4; ++mb)
#pragma unroll
      for (int nb = 0; nb < 4; ++nb)
        acc[mb][nb] += *(const f32x4*)&src[(nb * 16 + c) * 68 + mb * 16 + q * 4];
    if (q == 0)
#pragma unroll
      for (int nb = 0; nb < 4; ++nb) lv[nb] += lredA[wave][nb * 16 + c];
  }
  __syncthreads();
  if (wave == 1) {
#pragma unroll
    for (int mb = 0; mb < 4; ++mb)
#pragma unroll
      for (int nb = 0; nb < 4; ++nb)
        *(f32x4*)&red[0][(nb * 16 + c) * 68 + mb * 16 + q * 4] = acc[mb][nb];
    if (q == 0)
#pragma unroll
      for (int nb = 0; nb < 4; ++nb) lredB[nb * 16 + c] = lv[nb];
  }
  __syncthreads();
  if (wave == 0) {
    float* out = slab + ((h * 32 + jc) * 4 + ic) * 4096;
#pragma unroll
    for (int mb = 0; mb < 4; ++mb)
#pragma unroll
      for (int nb = 0; nb < 4; ++nb) {
        f32x4 v = acc[mb][nb] +
                  *(const f32x4*)&red[0][(nb * 16 + c) * 68 + mb * 16 + q * 4];
        *(f32x4*)(out + (nb * 16 + c) * 64 + mb * 16 + q * 4) = v;
      }
    if (q == 0)
#pragma unroll
      for (int nb = 0; nb < 4; ++nb)
        lslab[(h * 32 + jc) * 256 + ic * 64 + nb * 16 + c] =
            lv[nb] + lredB[nb * 16 + c];
  }
}

// ---------------------------------------------------------------------------
// Kernel 3: reduce 32 j-chunk partials, normalize, head re-interleave.
// Vectorized f32x4: 32768 threads = 128 blocks.  [R12 frozen]
// ---------------------------------------------------------------------------
__global__ __launch_bounds__(256) void reduce_kernel(
    const float* __restrict__ slab, const float* __restrict__ lslab,
    float* __restrict__ yn) {
  int idx = blockIdx.x * 256 + threadIdx.x;  // 32768 = 8h*4ic*64il*16dg
  int h = idx >> 12;
  int r = idx & 4095;
  int ic = r >> 10;
  int il = (r >> 4) & 63;
  int d4 = (r & 15) * 4;
  f32x4 s = {0.f, 0.f, 0.f, 0.f};
  float l = 0.f;
#pragma unroll 4
  for (int jc = 0; jc < 32; ++jc) {
    s += *(const f32x4*)&slab[(((h * 32 + jc) * 4 + ic) << 12) + il * 64 + d4];
    l += lslab[(h * 32 + jc) * 256 + ic * 64 + il];
  }
  int i = ic * 64 + il;
  float rl = 1.f / l;
  f32x4 o = {s.x * rl, s.y * rl, s.z * rl, s.w * rl};
  *(f32x4*)&yn[i * C_ + h * 64 + d4] = o;
}

// ---------------------------------------------------------------------------
// Kernel 4: out = yn[256,512] @ W_out[512,512] + b_out
// BM=16, BN=64, BK=32; grid (8,16) = 128 blocks.
// R13: register-prefetch double-buffered k-loop.
// ---------------------------------------------------------------------------
__global__ __launch_bounds__(256) void out_gemm(
    const float* __restrict__ A, const float* __restrict__ W,
    const float* __restrict__ b, float* __restrict__ out) {
  __shared__ float As[32][17];
  __shared__ float Bs[32][68];
  const int bx = blockIdx.x;
  const int by = blockIdx.y;
  const int tid = threadIdx.x;
  const int m = tid >> 4;
  const int c4 = (tid & 15) * 4;
  float acc0 = 0.f, acc1 = 0.f, acc2 = 0.f, acc3 = 0.f;

  const int lk = tid & 31;
  const int lm = tid >> 5;
  const int bk = tid >> 4;

  float a0r = A[(by * 16 + lm) * C_ + lk];
  float a1r = A[(by * 16 + lm + 8) * C_ + lk];
  f32x4 b0r = *(const f32x4*)&W[bk * C_ + bx * 64 + c4];
  f32x4 b1r = *(const f32x4*)&W[(bk + 16) * C_ + bx * 64 + c4];

  for (int k0 = 0; k0 < C_; k0 += 32) {
    As[lk][lm] = a0r;
    As[lk][lm + 8] = a1r;
    *(f32x4*)&Bs[bk][c4] = b0r;
    *(f32x4*)&Bs[bk + 16][c4] = b1r;
    __syncthreads();
    if (k0 + 32 < C_) {
      a0r = A[(by * 16 + lm) * C_ + k0 + 32 + lk];
      a1r = A[(by * 16 + lm + 8) * C_ + k0 + 32 + lk];
      b0r = *(const f32x4*)&W[(k0 + 32 + bk) * C_ + bx * 64 + c4];
      b1r = *(const f32x4*)&W[(k0 + 32 + bk + 16) * C_ + bx * 64 + c4];
    }
#pragma unroll
    for (int kq = 0; kq < 32; ++kq) {
      float a = As[kq][m];
      f32x4 bv = *(const f32x4*)&Bs[kq][c4];
      acc0 += a * bv.x; acc1 += a * bv.y; acc2 += a * bv.z; acc3 += a * bv.w;
    }
    __syncthreads();
  }

  const int i = by * 16 + m;
  const int col = bx * 64 + c4;
  f32x4 o = {acc0 + b[col + 0], acc1 + b[col + 1], acc2 + b[col + 2],
             acc3 + b[col + 3]};
  *(f32x4*)(out + i * C_ + col) = o;
}

// ---------------------------------------------------------------------------
extern "C" void kernel_launch(void* const* d_in, const int* in_sizes, int n_in,
                              void* d_out, int out_size, void* d_ws,
                              size_t ws_size, hipStream_t stream) {
  const float* x     = (const float*)d_in[0];
  const float* W_att = (const float*)d_in[1];
  const float* b_att = (const float*)d_in[2];
  const float* W_out = (const float*)d_in[3];
  const float* b_out = (const float*)d_in[4];

  char* ws = (char*)d_ws;
  float* slab           = (float*)(ws + 0);         // 16777216 B
  float* lslab          = (float*)(ws + 16777216);  //   262144 B
  float* qSb            = (float*)(ws + 17039360);  //   524288 B
  float* kj             = (float*)(ws + 17563648);  //   524288 B
  unsigned short* kkB   = (unsigned short*)(ws + 18087936);  // 262144 B
  float* vj             = (float*)(ws + 18350080);  //   524288 B
  float* vkT            = (float*)(ws + 18874368);  //   524288 B
  float* yn             = (float*)(ws + 19398656);  //   524288 B

  proj_kernel<<<dim3(40, 16), 256, 0, stream>>>(x, W_att, b_att, qSb, kj, kkB,
                                                vj, vkT);
  flash3_kernel<<<dim3(32, 4, 8), 256, 0, stream>>>(qSb, kj, kkB, vj, vkT,
                                                    slab, lslab);
  reduce_kernel<<<dim3(128), 256, 0, stream>>>(slab, lslab, yn);
  out_gemm<<<dim3(8, 16), 256, 0, stream>>>(yn, W_out, b_out, (float*)d_out);
}